// Round 1
// baseline (1705.175 us; speedup 1.0000x reference)
//
#include <hip/hip_runtime.h>
#include <hip/hip_bf16.h>

// ---------------------------------------------------------------------------
// GAT x3 + fc + MLP baseline, fp32 everywhere.
// Pipeline per call:
//   1. probe edge_index storage (int64 vs int32) on-device, convert to int32
//   2. build CSR over dst (counts -> scan -> fill); self-loops implicit
//   3. per GAT layer: GEMM h=x@W ; al_s/al_d ; segment max+sum ; aggregate
//   4. rot = h @ fc_w + fc_b ; MLP branch for root_norm
// ---------------------------------------------------------------------------

#define GAT_SLOPE 0.2f
#define ACT_SLOPE 0.01f

__device__ __forceinline__ float lrelu(float x, float s) {
    return x > 0.f ? x : s * x;
}

// ---------------- edge-index format probe + convert ----------------
__global__ void detect_fmt(const int* __restrict__ raw, int nwords, int* flag) {
    __shared__ int nz;
    if (threadIdx.x == 0) nz = 0;
    __syncthreads();
    int lim = nwords < 4096 ? nwords : 4096;
    for (int i = threadIdx.x * 2 + 1; i < lim; i += 512)
        if (raw[i] != 0) atomicAdd(&nz, 1);
    __syncthreads();
    if (threadIdx.x == 0) *flag = (nz == 0) ? 1 : 0;   // 1 => int64 storage
}

__global__ void convert_idx(const int* __restrict__ raw, int n,
                            const int* __restrict__ flag, int* __restrict__ out) {
    int i = blockIdx.x * blockDim.x + threadIdx.x;
    if (i < n) out[i] = (*flag) ? raw[2 * i] : raw[i];
}

// ---------------- CSR build ----------------
__global__ void zero_ints(int* a, int n) {
    int i = blockIdx.x * blockDim.x + threadIdx.x;
    if (i < n) a[i] = 0;
}

__global__ void edge_count(const int* __restrict__ dst, int E, int* __restrict__ counts) {
    int i = blockIdx.x * blockDim.x + threadIdx.x;
    if (i < E) atomicAdd(&counts[dst[i]], 1);
}

__global__ void scan_block(const int* __restrict__ counts, int* __restrict__ inc,
                           int* __restrict__ blockSums, int N) {
    __shared__ int sh[256];
    int i = blockIdx.x * 256 + threadIdx.x;
    int v = (i < N) ? counts[i] : 0;
    sh[threadIdx.x] = v;
    __syncthreads();
    for (int off = 1; off < 256; off <<= 1) {
        int t = (threadIdx.x >= off) ? sh[threadIdx.x - off] : 0;
        __syncthreads();
        sh[threadIdx.x] += t;
        __syncthreads();
    }
    if (i < N) inc[i] = sh[threadIdx.x];
    if (threadIdx.x == 255) blockSums[blockIdx.x] = sh[255];
}

__global__ void scan_sums(int* __restrict__ blockSums, int nb, int* __restrict__ row_ptr) {
    __shared__ int sh[512];
    int v = ((int)threadIdx.x < nb) ? blockSums[threadIdx.x] : 0;
    sh[threadIdx.x] = v;
    __syncthreads();
    for (int off = 1; off < 512; off <<= 1) {
        int t = (threadIdx.x >= off) ? sh[threadIdx.x - off] : 0;
        __syncthreads();
        sh[threadIdx.x] += t;
        __syncthreads();
    }
    if ((int)threadIdx.x < nb) blockSums[threadIdx.x] = sh[threadIdx.x];
    if (threadIdx.x == 0) row_ptr[0] = 0;
}

__global__ void scan_add(const int* __restrict__ inc, const int* __restrict__ blockSums,
                         int* __restrict__ row_ptr, int N) {
    int i = blockIdx.x * 256 + threadIdx.x;
    if (i < N) row_ptr[i + 1] = inc[i] + (blockIdx.x > 0 ? blockSums[blockIdx.x - 1] : 0);
}

__global__ void edge_fill(const int* __restrict__ src, const int* __restrict__ dst, int E,
                          const int* __restrict__ row_ptr, int* __restrict__ cursor,
                          int* __restrict__ col) {
    int i = blockIdx.x * blockDim.x + threadIdx.x;
    if (i < E) {
        int d = dst[i];
        int pos = row_ptr[d] + atomicAdd(&cursor[d], 1);
        col[pos] = src[i];
    }
}

// ---------------- generic fp32 tiled GEMM (+bias, +optional lrelu) ----------------
// C[M,N] = A[M,K] @ B[K,N] (+ bias[N]) (+ lrelu(slope))
__global__ __launch_bounds__(256) void gemm_f32(
    const float* __restrict__ A, const float* __restrict__ B,
    const float* __restrict__ bias, float* __restrict__ C,
    int M, int N, int K, int act, float slope) {
    __shared__ float As[64][17];
    __shared__ float Bs[16][64];
    int t = threadIdx.x;
    int tr = t >> 4, tc = t & 15;
    int rowBase = blockIdx.y * 64;
    int colBase = blockIdx.x * 64;
    float acc[4][4] = {};
    for (int k0 = 0; k0 < K; k0 += 16) {
        {
            int m = t >> 2;
            int k = (t & 3) * 4;
            int gr = rowBase + m;
#pragma unroll
            for (int i = 0; i < 4; i++) {
                int gk = k0 + k + i;
                As[m][k + i] = (gr < M && gk < K) ? A[(long)gr * K + gk] : 0.f;
            }
        }
        {
            int kk = t >> 4;
            int n = (t & 15) * 4;
            int gk = k0 + kk;
#pragma unroll
            for (int i = 0; i < 4; i++) {
                int gn = colBase + n + i;
                Bs[kk][n + i] = (gk < K && gn < N) ? B[(long)gk * N + gn] : 0.f;
            }
        }
        __syncthreads();
#pragma unroll
        for (int kk = 0; kk < 16; kk++) {
            float a[4], b[4];
#pragma unroll
            for (int i = 0; i < 4; i++) a[i] = As[tr * 4 + i][kk];
#pragma unroll
            for (int j = 0; j < 4; j++) b[j] = Bs[kk][tc * 4 + j];
#pragma unroll
            for (int i = 0; i < 4; i++)
#pragma unroll
                for (int j = 0; j < 4; j++) acc[i][j] += a[i] * b[j];
        }
        __syncthreads();
    }
#pragma unroll
    for (int i = 0; i < 4; i++) {
        int r = rowBase + tr * 4 + i;
        if (r >= M) continue;
#pragma unroll
        for (int j = 0; j < 4; j++) {
            int c = colBase + tc * 4 + j;
            if (c >= N) continue;
            float v = acc[i][j] + (bias ? bias[c] : 0.f);
            if (act) v = lrelu(v, slope);
            C[(long)r * N + c] = v;
        }
    }
}

// ---------------- attention logits: al_s/al_d per (node, head) ----------------
// h laid out [N, 4*64]; index idx = n*4 + head addresses h + idx*64.
__global__ void gat_al(const float* __restrict__ h, const float* __restrict__ a_src,
                       const float* __restrict__ a_dst, float* __restrict__ al_s,
                       float* __restrict__ al_d, int N4) {
    int idx = blockIdx.x * blockDim.x + threadIdx.x;
    if (idx >= N4) return;
    int hh = idx & 3;
    const float4* hv = (const float4*)(h + (long)idx * 64);
    const float4* as = (const float4*)(a_src + hh * 64);
    const float4* ad = (const float4*)(a_dst + hh * 64);
    float ss = 0.f, sd = 0.f;
#pragma unroll
    for (int i = 0; i < 16; i++) {
        float4 x = hv[i], u = as[i], v = ad[i];
        ss += x.x * u.x + x.y * u.y + x.z * u.z + x.w * u.w;
        sd += x.x * v.x + x.y * v.y + x.z * v.z + x.w * v.w;
    }
    al_s[idx] = ss;
    al_d[idx] = sd;
}

// ---------------- segment max + sum (gather over incoming edges + self loop) ----
__global__ void gat_ms(const float* __restrict__ al_s, const float* __restrict__ al_d,
                       const int* __restrict__ row_ptr, const int* __restrict__ col,
                       float* __restrict__ mArr, float* __restrict__ rsArr, int N4) {
    int idx = blockIdx.x * blockDim.x + threadIdx.x;
    if (idx >= N4) return;
    int n = idx >> 2, hh = idx & 3;
    float ad = al_d[idx];
    float eself = lrelu(al_s[idx] + ad, GAT_SLOPE);
    float m = eself;
    int beg = row_ptr[n], end = row_ptr[n + 1];
    for (int i = beg; i < end; i++) {
        float e = lrelu(al_s[col[i] * 4 + hh] + ad, GAT_SLOPE);
        m = fmaxf(m, e);
    }
    float s = expf(eself - m);
    for (int i = beg; i < end; i++) {
        float e = lrelu(al_s[col[i] * 4 + hh] + ad, GAT_SLOPE);
        s += expf(e - m);
    }
    mArr[idx] = m;
    rsArr[idx] = 1.f / s;
}

// ---------------- aggregation: one wave per node ----------------
__global__ __launch_bounds__(256) void gat_agg(
    const float* __restrict__ h, const float* __restrict__ al_s,
    const float* __restrict__ al_d, const float* __restrict__ mArr,
    const float* __restrict__ rsArr, const int* __restrict__ row_ptr,
    const int* __restrict__ col, const float* __restrict__ bias,
    float* __restrict__ out, int N, int act, float slope) {
    int gw = (blockIdx.x * 256 + threadIdx.x) >> 6;   // node id, wave-uniform
    if (gw >= N) return;
    int lane = threadIdx.x & 63;
    int head = lane >> 4;
    int n = gw;
    int idx = n * 4 + head;
    float ad = al_d[idx], m = mArr[idx], rs = rsArr[idx];
    const float4* h4 = (const float4*)h;
    // self loop
    float e = lrelu(al_s[idx] + ad, GAT_SLOPE);
    float w = expf(e - m) * rs;
    float4 hv = h4[(long)n * 64 + lane];
    float4 acc;
    acc.x = w * hv.x; acc.y = w * hv.y; acc.z = w * hv.z; acc.w = w * hv.w;
    int beg = row_ptr[n], end = row_ptr[n + 1];
    for (int i = beg; i < end; i++) {
        int src = col[i];
        float e2 = lrelu(al_s[src * 4 + head] + ad, GAT_SLOPE);
        float w2 = expf(e2 - m) * rs;
        float4 hv2 = h4[(long)src * 64 + lane];
        acc.x += w2 * hv2.x; acc.y += w2 * hv2.y;
        acc.z += w2 * hv2.z; acc.w += w2 * hv2.w;
    }
    float4 bv = ((const float4*)bias)[lane];
    acc.x += bv.x; acc.y += bv.y; acc.z += bv.z; acc.w += bv.w;
    if (act) {
        acc.x = lrelu(acc.x, slope); acc.y = lrelu(acc.y, slope);
        acc.z = lrelu(acc.z, slope); acc.w = lrelu(acc.w, slope);
    }
    ((float4*)out)[(long)n * 64 + lane] = acc;
}

// ---------------------------------------------------------------------------
extern "C" void kernel_launch(void* const* d_in, const int* in_sizes, int n_in,
                              void* d_out, int out_size, void* d_ws, size_t ws_size,
                              hipStream_t stream) {
    const float* x        = (const float*)d_in[0];
    const int*   rawEdge  = (const int*)d_in[1];
    const float* rootCtx  = (const float*)d_in[2];
    const float* W[3]     = {(const float*)d_in[3], (const float*)d_in[7], (const float*)d_in[11]};
    const float* aS[3]    = {(const float*)d_in[4], (const float*)d_in[8], (const float*)d_in[12]};
    const float* aD[3]    = {(const float*)d_in[5], (const float*)d_in[9], (const float*)d_in[13]};
    const float* bb[3]    = {(const float*)d_in[6], (const float*)d_in[10], (const float*)d_in[14]};
    const float* fc_w     = (const float*)d_in[15];
    const float* fc_b     = (const float*)d_in[16];
    const float* r_w1     = (const float*)d_in[17];
    const float* r_b1     = (const float*)d_in[18];
    const float* r_w2     = (const float*)d_in[19];
    const float* r_b2     = (const float*)d_in[20];
    const float* r_w3     = (const float*)d_in[21];
    const float* r_b3     = (const float*)d_in[22];

    const int N  = in_sizes[0] / 80;      // 102400
    const int E  = in_sizes[1] / 2;       // 409600
    const int R  = in_sizes[2] / 60;      // 4096
    const int N4 = N * 4;
    const int HC = 256;

    float* outRot  = (float*)d_out;             // [N, 80]
    float* outRoot = (float*)d_out + (long)N * 80;  // [R, 60]

    // ---- carve workspace ----
    size_t off = 0;
    auto carve = [&](size_t bytes) -> void* {
        off = (off + 255) & ~(size_t)255;
        void* p = (char*)d_ws + off;
        off += bytes;
        return p;
    };
    int*   flag      = (int*)carve(4);
    int*   idx32     = (int*)carve((size_t)2 * E * 4);
    int*   counts    = (int*)carve((size_t)N * 4);
    int*   cursor    = (int*)carve((size_t)N * 4);
    int*   row_ptr   = (int*)carve((size_t)(N + 1) * 4);
    int*   incArr    = (int*)carve((size_t)N * 4);
    int*   blockSums = (int*)carve(512 * 4);
    int*   colArr    = (int*)carve((size_t)E * 4);
    float* al_s      = (float*)carve((size_t)N4 * 4);
    float* al_d      = (float*)carve((size_t)N4 * 4);
    float* mArr      = (float*)carve((size_t)N4 * 4);
    float* rsArr     = (float*)carve((size_t)N4 * 4);
    float* hA        = (float*)carve((size_t)N * HC * 4);
    float* hB        = (float*)carve((size_t)N * HC * 4);
    float* t1        = (float*)carve((size_t)R * 512 * 4);
    float* t2        = (float*)carve((size_t)R * 512 * 4);

    const int nb = (N + 255) / 256;   // scan blocks (400)

    // ---- edge format + CSR build ----
    detect_fmt<<<1, 256, 0, stream>>>(rawEdge, 2 * E, flag);
    convert_idx<<<(2 * E + 255) / 256, 256, 0, stream>>>(rawEdge, 2 * E, flag, idx32);
    const int* srcArr = idx32;
    const int* dstArr = idx32 + E;
    zero_ints<<<(N + 255) / 256, 256, 0, stream>>>(counts, N);
    zero_ints<<<(N + 255) / 256, 256, 0, stream>>>(cursor, N);
    edge_count<<<(E + 255) / 256, 256, 0, stream>>>(dstArr, E, counts);
    scan_block<<<nb, 256, 0, stream>>>(counts, incArr, blockSums, N);
    scan_sums<<<1, 512, 0, stream>>>(blockSums, nb, row_ptr);
    scan_add<<<nb, 256, 0, stream>>>(incArr, blockSums, row_ptr, N);
    edge_fill<<<(E + 255) / 256, 256, 0, stream>>>(srcArr, dstArr, E, row_ptr, cursor, colArr);

    dim3 blk(256);
    // ---- GAT layers ----
    const float* cur = x;
    int curK = 80;
    for (int l = 0; l < 3; l++) {
        dim3 g1((HC + 63) / 64, (N + 63) / 64);
        gemm_f32<<<g1, blk, 0, stream>>>(cur, W[l], nullptr, hA, N, HC, curK, 0, 0.f);
        gat_al<<<(N4 + 255) / 256, blk, 0, stream>>>(hA, aS[l], aD[l], al_s, al_d, N4);
        gat_ms<<<(N4 + 255) / 256, blk, 0, stream>>>(al_s, al_d, row_ptr, colArr, mArr, rsArr, N4);
        int act = (l < 2) ? 1 : 0;
        gat_agg<<<(N * 64 + 255) / 256, blk, 0, stream>>>(hA, al_s, al_d, mArr, rsArr,
                                                          row_ptr, colArr, bb[l], hB, N,
                                                          act, ACT_SLOPE);
        cur = hB;
        curK = HC;
    }

    // ---- rot = h @ fc_w + fc_b ----
    {
        dim3 g((80 + 63) / 64, (N + 63) / 64);
        gemm_f32<<<g, blk, 0, stream>>>(hB, fc_w, fc_b, outRot, N, 80, HC, 0, 0.f);
    }
    // ---- MLP branch ----
    {
        dim3 g1((512 + 63) / 64, (R + 63) / 64);
        gemm_f32<<<g1, blk, 0, stream>>>(rootCtx, r_w1, r_b1, t1, R, 512, 60, 1, ACT_SLOPE);
        dim3 g2((512 + 63) / 64, (R + 63) / 64);
        gemm_f32<<<g2, blk, 0, stream>>>(t1, r_w2, r_b2, t2, R, 512, 512, 1, ACT_SLOPE);
        dim3 g3((60 + 63) / 64, (R + 63) / 64);
        gemm_f32<<<g3, blk, 0, stream>>>(t2, r_w3, r_b3, outRoot, R, 60, 512, 0, 0.f);
    }
}

// Round 2
// 857.447 us; speedup vs baseline: 1.9887x; 1.9887x over previous
//
#include <hip/hip_runtime.h>
#include <hip/hip_bf16.h>

// ---------------------------------------------------------------------------
// GAT x3 + fc + MLP. GEMMs in bf16 MFMA (16x16x32), attention/aggregation fp32.
// Pipeline per call:
//   1. probe edge_index storage (int64 vs int32) on-device, convert to int32
//   2. build CSR over dst (counts -> scan -> fill); self-loops implicit
//   3. convert weights (transposed [N,K] bf16) + x once
//   4. per GAT layer: MFMA GEMM h=x@W (fp32 out) ; al_s/al_d ; segment
//      max+sum ; aggregate (writes bf16 h for next GEMM)
//   5. rot = h @ fc_w + fc_b (MFMA) ; MLP branch (middle GEMM MFMA)
// ---------------------------------------------------------------------------

#define GAT_SLOPE 0.2f
#define ACT_SLOPE 0.01f

typedef unsigned short ushort_t;
typedef __attribute__((ext_vector_type(8))) short bf16x8;
typedef __attribute__((ext_vector_type(8))) unsigned short ushort8;
typedef __attribute__((ext_vector_type(4))) unsigned short ushort4v;
typedef __attribute__((ext_vector_type(4))) float floatx4;

__device__ __forceinline__ float lrelu(float x, float s) {
    return x > 0.f ? x : s * x;
}

__device__ __forceinline__ ushort_t f2bf(float f) {
    union { float f; unsigned u; } x; x.f = f;
    unsigned r = x.u + 0x7FFF + ((x.u >> 16) & 1);   // round-nearest-even
    return (ushort_t)(r >> 16);
}

// ---------------- edge-index format probe + convert ----------------
__global__ void detect_fmt(const int* __restrict__ raw, int nwords, int* flag) {
    __shared__ int nz;
    if (threadIdx.x == 0) nz = 0;
    __syncthreads();
    int lim = nwords < 4096 ? nwords : 4096;
    for (int i = threadIdx.x * 2 + 1; i < lim; i += 512)
        if (raw[i] != 0) atomicAdd(&nz, 1);
    __syncthreads();
    if (threadIdx.x == 0) *flag = (nz == 0) ? 1 : 0;   // 1 => int64 storage
}

__global__ void convert_idx(const int* __restrict__ raw, int n,
                            const int* __restrict__ flag, int* __restrict__ out) {
    int i = blockIdx.x * blockDim.x + threadIdx.x;
    if (i < n) out[i] = (*flag) ? raw[2 * i] : raw[i];
}

// ---------------- CSR build ----------------
__global__ void zero_ints(int* a, int n) {
    int i = blockIdx.x * blockDim.x + threadIdx.x;
    if (i < n) a[i] = 0;
}

__global__ void edge_count(const int* __restrict__ dst, int E, int* __restrict__ counts) {
    int i = blockIdx.x * blockDim.x + threadIdx.x;
    if (i < E) atomicAdd(&counts[dst[i]], 1);
}

__global__ void scan_block(const int* __restrict__ counts, int* __restrict__ inc,
                           int* __restrict__ blockSums, int N) {
    __shared__ int sh[256];
    int i = blockIdx.x * 256 + threadIdx.x;
    int v = (i < N) ? counts[i] : 0;
    sh[threadIdx.x] = v;
    __syncthreads();
    for (int off = 1; off < 256; off <<= 1) {
        int t = (threadIdx.x >= off) ? sh[threadIdx.x - off] : 0;
        __syncthreads();
        sh[threadIdx.x] += t;
        __syncthreads();
    }
    if (i < N) inc[i] = sh[threadIdx.x];
    if (threadIdx.x == 255) blockSums[blockIdx.x] = sh[255];
}

__global__ void scan_sums(int* __restrict__ blockSums, int nb, int* __restrict__ row_ptr) {
    __shared__ int sh[512];
    int v = ((int)threadIdx.x < nb) ? blockSums[threadIdx.x] : 0;
    sh[threadIdx.x] = v;
    __syncthreads();
    for (int off = 1; off < 512; off <<= 1) {
        int t = (threadIdx.x >= off) ? sh[threadIdx.x - off] : 0;
        __syncthreads();
        sh[threadIdx.x] += t;
        __syncthreads();
    }
    if ((int)threadIdx.x < nb) blockSums[threadIdx.x] = sh[threadIdx.x];
    if (threadIdx.x == 0) row_ptr[0] = 0;
}

__global__ void scan_add(const int* __restrict__ inc, const int* __restrict__ blockSums,
                         int* __restrict__ row_ptr, int N) {
    int i = blockIdx.x * 256 + threadIdx.x;
    if (i < N) row_ptr[i + 1] = inc[i] + (blockIdx.x > 0 ? blockSums[blockIdx.x - 1] : 0);
}

__global__ void edge_fill(const int* __restrict__ src, const int* __restrict__ dst, int E,
                          const int* __restrict__ row_ptr, int* __restrict__ cursor,
                          int* __restrict__ col) {
    int i = blockIdx.x * blockDim.x + threadIdx.x;
    if (i < E) {
        int d = dst[i];
        int pos = row_ptr[d] + atomicAdd(&cursor[d], 1);
        col[pos] = src[i];
    }
}

// ---------------- conversions ----------------
__global__ void convert_bf4(const float* __restrict__ in, ushort_t* __restrict__ out, int n4) {
    int i = blockIdx.x * blockDim.x + threadIdx.x;
    if (i >= n4) return;
    const float4 v = ((const float4*)in)[i];
    ushort4v o;
    o.x = f2bf(v.x); o.y = f2bf(v.y); o.z = f2bf(v.z); o.w = f2bf(v.w);
    ((ushort4v*)out)[i] = o;
}

// in: [K,N] fp32 ; out: [Npad,K] bf16 (transposed, zero-padded rows >= N)
__global__ void convert_w(const float* __restrict__ in, ushort_t* __restrict__ out,
                          int K, int N, int Npad) {
    int i = blockIdx.x * blockDim.x + threadIdx.x;
    if (i >= Npad * K) return;
    int n = i / K, k = i - n * K;
    float v = (n < N) ? in[(size_t)k * N + n] : 0.f;
    out[i] = f2bf(v);
}

// ---------------- bf16 MFMA GEMM ----------------
// C[M,N] = A[M,K]_bf16 @ B  where Bt[Npad,K]_bf16 = B^T (+bias) (+lrelu)
// grid (Npad/128, M/128), block 256. M must be multiple of 128; K multiple of 8.
#define LDA 40   // padded LDS row (elements): row stride 80B -> 2-way bank alias only

__global__ __launch_bounds__(256) void gemm_mfma(
    const ushort_t* __restrict__ A, const ushort_t* __restrict__ Bt,
    const float* __restrict__ bias, float* __restrict__ C,
    int M, int N, int K, int act, float slope) {
    __shared__ __align__(16) ushort_t As[128 * LDA];
    __shared__ __align__(16) ushort_t Bs[128 * LDA];
    int t = threadIdx.x;
    int wave = t >> 6, lane = t & 63;
    int wm = (wave >> 1) << 6;          // 0 / 64
    int wn = (wave & 1) << 6;
    int rowBase = blockIdx.y << 7;
    int colBase = blockIdx.x << 7;
    int lrow = lane & 15, lquad = lane >> 4;
    floatx4 acc[4][4];
#pragma unroll
    for (int i = 0; i < 4; i++)
#pragma unroll
        for (int j = 0; j < 4; j++) acc[i][j] = (floatx4){0.f, 0.f, 0.f, 0.f};

    int srow = t >> 2;              // 0..63
    int sko  = (t & 3) * 8;         // 0,8,16,24
    const ushort8 zero8 = {0, 0, 0, 0, 0, 0, 0, 0};

    for (int k0 = 0; k0 < K; k0 += 32) {
        bool kin = (k0 + sko + 8) <= K;
#pragma unroll
        for (int half = 0; half < 2; half++) {
            int row = srow + half * 64;
            ushort8 va = kin ? *(const ushort8*)(A + (size_t)(rowBase + row) * K + k0 + sko)
                             : zero8;
            *(ushort8*)(As + row * LDA + sko) = va;
            ushort8 vb = kin ? *(const ushort8*)(Bt + (size_t)(colBase + row) * K + k0 + sko)
                             : zero8;
            *(ushort8*)(Bs + row * LDA + sko) = vb;
        }
        __syncthreads();
        bf16x8 af[4], bfv[4];
#pragma unroll
        for (int i = 0; i < 4; i++)
            af[i] = *(const bf16x8*)(As + (wm + i * 16 + lrow) * LDA + lquad * 8);
#pragma unroll
        for (int j = 0; j < 4; j++)
            bfv[j] = *(const bf16x8*)(Bs + (wn + j * 16 + lrow) * LDA + lquad * 8);
#pragma unroll
        for (int i = 0; i < 4; i++)
#pragma unroll
            for (int j = 0; j < 4; j++)
                acc[i][j] = __builtin_amdgcn_mfma_f32_16x16x32_bf16(af[i], bfv[j],
                                                                    acc[i][j], 0, 0, 0);
        __syncthreads();
    }
    // epilogue: C/D layout col=lane&15, row=(lane>>4)*4+reg
#pragma unroll
    for (int i = 0; i < 4; i++) {
        int gr = rowBase + wm + i * 16 + lquad * 4;
#pragma unroll
        for (int j = 0; j < 4; j++) {
            int gc = colBase + wn + j * 16 + lrow;
            if (gc >= N) continue;
            float b = bias ? bias[gc] : 0.f;
#pragma unroll
            for (int r = 0; r < 4; r++) {
                float v = acc[i][j][r] + b;
                if (act) v = lrelu(v, slope);
                C[(size_t)(gr + r) * N + gc] = v;
            }
        }
    }
}

// ---------------- fp32 tiled GEMM (small MLP edges) ----------------
__global__ __launch_bounds__(256) void gemm_f32(
    const float* __restrict__ A, const float* __restrict__ B,
    const float* __restrict__ bias, float* __restrict__ C,
    int M, int N, int K, int act, float slope) {
    __shared__ float As[64][17];
    __shared__ float Bs[16][64];
    int t = threadIdx.x;
    int tr = t >> 4, tc = t & 15;
    int rowBase = blockIdx.y * 64;
    int colBase = blockIdx.x * 64;
    float acc[4][4] = {};
    for (int k0 = 0; k0 < K; k0 += 16) {
        {
            int m = t >> 2;
            int k = (t & 3) * 4;
            int gr = rowBase + m;
#pragma unroll
            for (int i = 0; i < 4; i++) {
                int gk = k0 + k + i;
                As[m][k + i] = (gr < M && gk < K) ? A[(size_t)gr * K + gk] : 0.f;
            }
        }
        {
            int kk = t >> 4;
            int n = (t & 15) * 4;
            int gk = k0 + kk;
#pragma unroll
            for (int i = 0; i < 4; i++) {
                int gn = colBase + n + i;
                Bs[kk][n + i] = (gk < K && gn < N) ? B[(size_t)gk * N + gn] : 0.f;
            }
        }
        __syncthreads();
#pragma unroll
        for (int kk = 0; kk < 16; kk++) {
            float a[4], b[4];
#pragma unroll
            for (int i = 0; i < 4; i++) a[i] = As[tr * 4 + i][kk];
#pragma unroll
            for (int j = 0; j < 4; j++) b[j] = Bs[kk][tc * 4 + j];
#pragma unroll
            for (int i = 0; i < 4; i++)
#pragma unroll
                for (int j = 0; j < 4; j++) acc[i][j] += a[i] * b[j];
        }
        __syncthreads();
    }
#pragma unroll
    for (int i = 0; i < 4; i++) {
        int r = rowBase + tr * 4 + i;
        if (r >= M) continue;
#pragma unroll
        for (int j = 0; j < 4; j++) {
            int c = colBase + tc * 4 + j;
            if (c >= N) continue;
            float v = acc[i][j] + (bias ? bias[c] : 0.f);
            if (act) v = lrelu(v, slope);
            C[(size_t)r * N + c] = v;
        }
    }
}

// ---------------- attention logits per (node, head) ----------------
__global__ void gat_al(const float* __restrict__ h, const float* __restrict__ a_src,
                       const float* __restrict__ a_dst, float* __restrict__ al_s,
                       float* __restrict__ al_d, int N4) {
    int idx = blockIdx.x * blockDim.x + threadIdx.x;
    if (idx >= N4) return;
    int hh = idx & 3;
    const float4* hv = (const float4*)(h + (size_t)idx * 64);
    const float4* as = (const float4*)(a_src + hh * 64);
    const float4* ad = (const float4*)(a_dst + hh * 64);
    float ss = 0.f, sd = 0.f;
#pragma unroll
    for (int i = 0; i < 16; i++) {
        float4 x = hv[i], u = as[i], v = ad[i];
        ss += x.x * u.x + x.y * u.y + x.z * u.z + x.w * u.w;
        sd += x.x * v.x + x.y * v.y + x.z * v.z + x.w * v.w;
    }
    al_s[idx] = ss;
    al_d[idx] = sd;
}

// ---------------- segment max + sum ----------------
__global__ void gat_ms(const float* __restrict__ al_s, const float* __restrict__ al_d,
                       const int* __restrict__ row_ptr, const int* __restrict__ col,
                       float* __restrict__ mArr, float* __restrict__ rsArr, int N4) {
    int idx = blockIdx.x * blockDim.x + threadIdx.x;
    if (idx >= N4) return;
    int n = idx >> 2, hh = idx & 3;
    float ad = al_d[idx];
    float eself = lrelu(al_s[idx] + ad, GAT_SLOPE);
    float m = eself;
    int beg = row_ptr[n], end = row_ptr[n + 1];
    for (int i = beg; i < end; i++) {
        float e = lrelu(al_s[col[i] * 4 + hh] + ad, GAT_SLOPE);
        m = fmaxf(m, e);
    }
    float s = expf(eself - m);
    for (int i = beg; i < end; i++) {
        float e = lrelu(al_s[col[i] * 4 + hh] + ad, GAT_SLOPE);
        s += expf(e - m);
    }
    mArr[idx] = m;
    rsArr[idx] = 1.f / s;
}

// ---------------- aggregation: one wave per node; writes bf16 h ----------------
__global__ __launch_bounds__(256) void gat_agg(
    const float* __restrict__ h, const float* __restrict__ al_s,
    const float* __restrict__ al_d, const float* __restrict__ mArr,
    const float* __restrict__ rsArr, const int* __restrict__ row_ptr,
    const int* __restrict__ col, const float* __restrict__ bias,
    ushort_t* __restrict__ out_bf, int N, int act, float slope) {
    int gw = (blockIdx.x * 256 + threadIdx.x) >> 6;   // node id, wave-uniform
    if (gw >= N) return;
    int lane = threadIdx.x & 63;
    int head = lane >> 4;
    int n = gw;
    int idx = n * 4 + head;
    float ad = al_d[idx], m = mArr[idx], rs = rsArr[idx];
    const float4* h4 = (const float4*)h;
    // self loop
    float e = lrelu(al_s[idx] + ad, GAT_SLOPE);
    float w = expf(e - m) * rs;
    float4 hv = h4[(size_t)n * 64 + lane];
    float4 acc;
    acc.x = w * hv.x; acc.y = w * hv.y; acc.z = w * hv.z; acc.w = w * hv.w;
    int beg = row_ptr[n], end = row_ptr[n + 1];
    for (int i = beg; i < end; i++) {
        int src = col[i];
        float e2 = lrelu(al_s[src * 4 + head] + ad, GAT_SLOPE);
        float w2 = expf(e2 - m) * rs;
        float4 hv2 = h4[(size_t)src * 64 + lane];
        acc.x += w2 * hv2.x; acc.y += w2 * hv2.y;
        acc.z += w2 * hv2.z; acc.w += w2 * hv2.w;
    }
    float4 bv = ((const float4*)bias)[lane];
    acc.x += bv.x; acc.y += bv.y; acc.z += bv.z; acc.w += bv.w;
    if (act) {
        acc.x = lrelu(acc.x, slope); acc.y = lrelu(acc.y, slope);
        acc.z = lrelu(acc.z, slope); acc.w = lrelu(acc.w, slope);
    }
    ushort4v o;
    o.x = f2bf(acc.x); o.y = f2bf(acc.y); o.z = f2bf(acc.z); o.w = f2bf(acc.w);
    ((ushort4v*)out_bf)[(size_t)n * 64 + lane] = o;
}

// ---------------------------------------------------------------------------
extern "C" void kernel_launch(void* const* d_in, const int* in_sizes, int n_in,
                              void* d_out, int out_size, void* d_ws, size_t ws_size,
                              hipStream_t stream) {
    const float* x        = (const float*)d_in[0];
    const int*   rawEdge  = (const int*)d_in[1];
    const float* rootCtx  = (const float*)d_in[2];
    const float* W[3]     = {(const float*)d_in[3], (const float*)d_in[7], (const float*)d_in[11]};
    const float* aS[3]    = {(const float*)d_in[4], (const float*)d_in[8], (const float*)d_in[12]};
    const float* aD[3]    = {(const float*)d_in[5], (const float*)d_in[9], (const float*)d_in[13]};
    const float* bb[3]    = {(const float*)d_in[6], (const float*)d_in[10], (const float*)d_in[14]};
    const float* fc_w     = (const float*)d_in[15];
    const float* fc_b     = (const float*)d_in[16];
    const float* r_w1     = (const float*)d_in[17];
    const float* r_b1     = (const float*)d_in[18];
    const float* r_w2     = (const float*)d_in[19];
    const float* r_b2     = (const float*)d_in[20];
    const float* r_w3     = (const float*)d_in[21];
    const float* r_b3     = (const float*)d_in[22];

    const int N  = in_sizes[0] / 80;      // 102400
    const int E  = in_sizes[1] / 2;       // 409600
    const int R  = in_sizes[2] / 60;      // 4096
    const int N4 = N * 4;
    const int HC = 256;

    float* outRot  = (float*)d_out;                  // [N, 80]
    float* outRoot = (float*)d_out + (size_t)N * 80; // [R, 60]

    // ---- carve workspace ----
    size_t off = 0;
    auto carve = [&](size_t bytes) -> void* {
        off = (off + 255) & ~(size_t)255;
        void* p = (char*)d_ws + off;
        off += bytes;
        return p;
    };
    int*     flag      = (int*)carve(4);
    int*     idx32     = (int*)carve((size_t)2 * E * 4);
    int*     counts    = (int*)carve((size_t)N * 4);
    int*     cursor    = (int*)carve((size_t)N * 4);
    int*     row_ptr   = (int*)carve((size_t)(N + 1) * 4);
    int*     incArr    = (int*)carve((size_t)N * 4);
    int*     blockSums = (int*)carve(512 * 4);
    int*     colArr    = (int*)carve((size_t)E * 4);
    float*   al_s      = (float*)carve((size_t)N4 * 4);
    float*   al_d      = (float*)carve((size_t)N4 * 4);
    float*   mArr      = (float*)carve((size_t)N4 * 4);
    float*   rsArr     = (float*)carve((size_t)N4 * 4);
    float*   hA        = (float*)carve((size_t)N * HC * 4);      // fp32 h (pre-agg)
    ushort_t* h_bf     = (ushort_t*)carve((size_t)N * HC * 2);   // bf16 A for next GEMM
    ushort_t* x_bf     = (ushort_t*)carve((size_t)N * 80 * 2);
    float*   t1        = (float*)carve((size_t)R * 512 * 4);
    float*   t2        = (float*)carve((size_t)R * 512 * 4);
    ushort_t* t1_bf    = (ushort_t*)carve((size_t)R * 512 * 2);
    ushort_t* Wt0      = (ushort_t*)carve((size_t)256 * 80 * 2);   // [256][80]
    ushort_t* Wt1      = (ushort_t*)carve((size_t)256 * 256 * 2);  // [256][256]
    ushort_t* Wt2      = (ushort_t*)carve((size_t)256 * 256 * 2);
    ushort_t* fcWt     = (ushort_t*)carve((size_t)128 * 256 * 2);  // [128pad][256]
    ushort_t* rWt2     = (ushort_t*)carve((size_t)512 * 512 * 2);  // [512][512]

    const int nb = (N + 255) / 256;   // scan blocks (400)
    dim3 blk(256);

    // ---- edge format + CSR build ----
    detect_fmt<<<1, 256, 0, stream>>>(rawEdge, 2 * E, flag);
    convert_idx<<<(2 * E + 255) / 256, 256, 0, stream>>>(rawEdge, 2 * E, flag, idx32);
    const int* srcArr = idx32;
    const int* dstArr = idx32 + E;
    zero_ints<<<(N + 255) / 256, 256, 0, stream>>>(counts, N);
    zero_ints<<<(N + 255) / 256, 256, 0, stream>>>(cursor, N);
    edge_count<<<(E + 255) / 256, 256, 0, stream>>>(dstArr, E, counts);
    scan_block<<<nb, 256, 0, stream>>>(counts, incArr, blockSums, N);
    scan_sums<<<1, 512, 0, stream>>>(blockSums, nb, row_ptr);
    scan_add<<<nb, 256, 0, stream>>>(incArr, blockSums, row_ptr, N);
    edge_fill<<<(E + 255) / 256, 256, 0, stream>>>(srcArr, dstArr, E, row_ptr, cursor, colArr);

    // ---- weight + input conversions ----
    convert_w<<<(256 * 80 + 255) / 256, blk, 0, stream>>>(W[0], Wt0, 80, 256, 256);
    convert_w<<<(256 * 256 + 255) / 256, blk, 0, stream>>>(W[1], Wt1, 256, 256, 256);
    convert_w<<<(256 * 256 + 255) / 256, blk, 0, stream>>>(W[2], Wt2, 256, 256, 256);
    convert_w<<<(128 * 256 + 255) / 256, blk, 0, stream>>>(fc_w, fcWt, 256, 80, 128);
    convert_w<<<(512 * 512 + 255) / 256, blk, 0, stream>>>(r_w2, rWt2, 512, 512, 512);
    convert_bf4<<<(N * 80 / 4 + 255) / 256, blk, 0, stream>>>(x, x_bf, N * 80 / 4);

    // ---- GAT layers ----
    const ushort_t* curA = x_bf;
    int curK = 80;
    for (int l = 0; l < 3; l++) {
        dim3 g1(HC / 128, N / 128);
        gemm_mfma<<<g1, blk, 0, stream>>>(curA, l == 0 ? Wt0 : (l == 1 ? Wt1 : Wt2),
                                          nullptr, hA, N, HC, curK, 0, 0.f);
        gat_al<<<(N4 + 255) / 256, blk, 0, stream>>>(hA, aS[l], aD[l], al_s, al_d, N4);
        gat_ms<<<(N4 + 255) / 256, blk, 0, stream>>>(al_s, al_d, row_ptr, colArr, mArr, rsArr, N4);
        int act = (l < 2) ? 1 : 0;
        gat_agg<<<(N * 64 + 255) / 256, blk, 0, stream>>>(hA, al_s, al_d, mArr, rsArr,
                                                          row_ptr, colArr, bb[l], h_bf, N,
                                                          act, ACT_SLOPE);
        curA = h_bf;
        curK = HC;
    }

    // ---- rot = h @ fc_w + fc_b  (N=80 real, tile padded to 128) ----
    {
        dim3 g(1, N / 128);
        gemm_mfma<<<g, blk, 0, stream>>>(h_bf, fcWt, fc_b, outRot, N, 80, HC, 0, 0.f);
    }
    // ---- MLP branch ----
    {
        dim3 g1((512 + 63) / 64, (R + 63) / 64);
        gemm_f32<<<g1, blk, 0, stream>>>(rootCtx, r_w1, r_b1, t1, R, 512, 60, 1, ACT_SLOPE);
        convert_bf4<<<(R * 512 / 4 + 255) / 256, blk, 0, stream>>>(t1, t1_bf, R * 512 / 4);
        dim3 g2(512 / 128, R / 128);
        gemm_mfma<<<g2, blk, 0, stream>>>(t1_bf, rWt2, r_b2, t2, R, 512, 512, 1, ACT_SLOPE);
        dim3 g3((60 + 63) / 64, (R + 63) / 64);
        gemm_f32<<<g3, blk, 0, stream>>>(t2, r_w3, r_b3, outRoot, R, 60, 512, 0, 0.f);
    }
}

// Round 3
// 653.049 us; speedup vs baseline: 2.6111x; 1.3130x over previous
//
#include <hip/hip_runtime.h>
#include <hip/hip_bf16.h>

// ---------------------------------------------------------------------------
// GAT x3 + fc + MLP. GEMMs in bf16 MFMA (16x16x32).
// R3: GEMM writes h in bf16 and computes attention logits (al_s/al_d) in its
// epilogue from fp32 accumulators (no atomics: each wave's 64-col window is
// exactly one head and K is complete per block). Aggregation is a single
// online-softmax pass gathering bf16 h rows (512 B/row, was 1 KB fp32).
// ---------------------------------------------------------------------------

#define GAT_SLOPE 0.2f
#define ACT_SLOPE 0.01f

typedef unsigned short ushort_t;
typedef __attribute__((ext_vector_type(8))) short bf16x8;
typedef __attribute__((ext_vector_type(8))) unsigned short ushort8;
typedef __attribute__((ext_vector_type(4))) unsigned short ushort4v;
typedef __attribute__((ext_vector_type(4))) float floatx4;

__device__ __forceinline__ float lrelu(float x, float s) {
    return x > 0.f ? x : s * x;
}

__device__ __forceinline__ ushort_t f2bf(float f) {
    union { float f; unsigned u; } x; x.f = f;
    unsigned r = x.u + 0x7FFF + ((x.u >> 16) & 1);   // round-nearest-even
    return (ushort_t)(r >> 16);
}

__device__ __forceinline__ float bf2f(ushort_t u) {
    union { unsigned u; float f; } x; x.u = ((unsigned)u) << 16;
    return x.f;
}

// ---------------- edge-index format probe + convert ----------------
__global__ void detect_fmt(const int* __restrict__ raw, int nwords, int* flag) {
    __shared__ int nz;
    if (threadIdx.x == 0) nz = 0;
    __syncthreads();
    int lim = nwords < 4096 ? nwords : 4096;
    for (int i = threadIdx.x * 2 + 1; i < lim; i += 512)
        if (raw[i] != 0) atomicAdd(&nz, 1);
    __syncthreads();
    if (threadIdx.x == 0) *flag = (nz == 0) ? 1 : 0;   // 1 => int64 storage
}

__global__ void convert_idx(const int* __restrict__ raw, int n,
                            const int* __restrict__ flag, int* __restrict__ out) {
    int i = blockIdx.x * blockDim.x + threadIdx.x;
    if (i < n) out[i] = (*flag) ? raw[2 * i] : raw[i];
}

// ---------------- CSR build ----------------
__global__ void zero_ints(int* a, int n) {
    int i = blockIdx.x * blockDim.x + threadIdx.x;
    if (i < n) a[i] = 0;
}

__global__ void edge_count(const int* __restrict__ dst, int E, int* __restrict__ counts) {
    int i = blockIdx.x * blockDim.x + threadIdx.x;
    if (i < E) atomicAdd(&counts[dst[i]], 1);
}

__global__ void scan_block(const int* __restrict__ counts, int* __restrict__ inc,
                           int* __restrict__ blockSums, int N) {
    __shared__ int sh[256];
    int i = blockIdx.x * 256 + threadIdx.x;
    int v = (i < N) ? counts[i] : 0;
    sh[threadIdx.x] = v;
    __syncthreads();
    for (int off = 1; off < 256; off <<= 1) {
        int t = (threadIdx.x >= off) ? sh[threadIdx.x - off] : 0;
        __syncthreads();
        sh[threadIdx.x] += t;
        __syncthreads();
    }
    if (i < N) inc[i] = sh[threadIdx.x];
    if (threadIdx.x == 255) blockSums[blockIdx.x] = sh[255];
}

__global__ void scan_sums(int* __restrict__ blockSums, int nb, int* __restrict__ row_ptr) {
    __shared__ int sh[512];
    int v = ((int)threadIdx.x < nb) ? blockSums[threadIdx.x] : 0;
    sh[threadIdx.x] = v;
    __syncthreads();
    for (int off = 1; off < 512; off <<= 1) {
        int t = (threadIdx.x >= off) ? sh[threadIdx.x - off] : 0;
        __syncthreads();
        sh[threadIdx.x] += t;
        __syncthreads();
    }
    if ((int)threadIdx.x < nb) blockSums[threadIdx.x] = sh[threadIdx.x];
    if (threadIdx.x == 0) row_ptr[0] = 0;
}

__global__ void scan_add(const int* __restrict__ inc, const int* __restrict__ blockSums,
                         int* __restrict__ row_ptr, int N) {
    int i = blockIdx.x * 256 + threadIdx.x;
    if (i < N) row_ptr[i + 1] = inc[i] + (blockIdx.x > 0 ? blockSums[blockIdx.x - 1] : 0);
}

__global__ void edge_fill(const int* __restrict__ src, const int* __restrict__ dst, int E,
                          const int* __restrict__ row_ptr, int* __restrict__ cursor,
                          int* __restrict__ col) {
    int i = blockIdx.x * blockDim.x + threadIdx.x;
    if (i < E) {
        int d = dst[i];
        int pos = row_ptr[d] + atomicAdd(&cursor[d], 1);
        col[pos] = src[i];
    }
}

// ---------------- conversions ----------------
__global__ void convert_bf4(const float* __restrict__ in, ushort_t* __restrict__ out, int n4) {
    int i = blockIdx.x * blockDim.x + threadIdx.x;
    if (i >= n4) return;
    const float4 v = ((const float4*)in)[i];
    ushort4v o;
    o.x = f2bf(v.x); o.y = f2bf(v.y); o.z = f2bf(v.z); o.w = f2bf(v.w);
    ((ushort4v*)out)[i] = o;
}

// in: [K,N] fp32 ; out: [Npad,K] bf16 (transposed, zero-padded rows >= N)
__global__ void convert_w(const float* __restrict__ in, ushort_t* __restrict__ out,
                          int K, int N, int Npad) {
    int i = blockIdx.x * blockDim.x + threadIdx.x;
    if (i >= Npad * K) return;
    int n = i / K, k = i - n * K;
    float v = (n < N) ? in[(size_t)k * N + n] : 0.f;
    out[i] = f2bf(v);
}

#define LDA 40   // padded LDS row (elements): row stride 80B -> 2-way bank alias only

// ---------------- fused GAT GEMM: H_bf16 = A @ W ; al_s/al_d from fp32 acc ----
// A[M,K]_bf16, Wt[256,K]_bf16 (=W^T). grid (2, M/128), block 256.
__global__ __launch_bounds__(256) void gemm_mfma_gat(
    const ushort_t* __restrict__ A, const ushort_t* __restrict__ Bt,
    const float* __restrict__ a_src, const float* __restrict__ a_dst,
    ushort_t* __restrict__ Hbf, float* __restrict__ al_s, float* __restrict__ al_d,
    int M, int K) {
    const int NCOL = 256;
    __shared__ __align__(16) ushort_t As[128 * LDA];
    __shared__ __align__(16) ushort_t Bs[128 * LDA];
    int t = threadIdx.x;
    int wave = t >> 6, lane = t & 63;
    int wm = (wave >> 1) << 6;          // 0 / 64
    int wn = (wave & 1) << 6;
    int rowBase = blockIdx.y << 7;
    int colBase = blockIdx.x << 7;
    int lrow = lane & 15, lquad = lane >> 4;
    floatx4 acc[4][4];
#pragma unroll
    for (int i = 0; i < 4; i++)
#pragma unroll
        for (int j = 0; j < 4; j++) acc[i][j] = (floatx4){0.f, 0.f, 0.f, 0.f};

    int srow = t >> 2;
    int sko  = (t & 3) * 8;
    const ushort8 zero8 = {0, 0, 0, 0, 0, 0, 0, 0};

    for (int k0 = 0; k0 < K; k0 += 32) {
        bool kin = (k0 + sko + 8) <= K;
#pragma unroll
        for (int half = 0; half < 2; half++) {
            int row = srow + half * 64;
            ushort8 va = kin ? *(const ushort8*)(A + (size_t)(rowBase + row) * K + k0 + sko)
                             : zero8;
            *(ushort8*)(As + row * LDA + sko) = va;
            ushort8 vb = kin ? *(const ushort8*)(Bt + (size_t)(colBase + row) * K + k0 + sko)
                             : zero8;
            *(ushort8*)(Bs + row * LDA + sko) = vb;
        }
        __syncthreads();
        bf16x8 af[4], bfv[4];
#pragma unroll
        for (int i = 0; i < 4; i++)
            af[i] = *(const bf16x8*)(As + (wm + i * 16 + lrow) * LDA + lquad * 8);
#pragma unroll
        for (int j = 0; j < 4; j++)
            bfv[j] = *(const bf16x8*)(Bs + (wn + j * 16 + lrow) * LDA + lquad * 8);
#pragma unroll
        for (int i = 0; i < 4; i++)
#pragma unroll
            for (int j = 0; j < 4; j++)
                acc[i][j] = __builtin_amdgcn_mfma_f32_16x16x32_bf16(af[i], bfv[j],
                                                                    acc[i][j], 0, 0, 0);
        __syncthreads();
    }
    // this wave's 64-col window = one head
    int head = (colBase + wn) >> 6;
    float avs[4], avd[4];
#pragma unroll
    for (int j = 0; j < 4; j++) {
        avs[j] = a_src[head * 64 + j * 16 + lrow];
        avd[j] = a_dst[head * 64 + j * 16 + lrow];
    }
#pragma unroll
    for (int i = 0; i < 4; i++) {
#pragma unroll
        for (int r = 0; r < 4; r++) {
            float ps = 0.f, pd = 0.f;
#pragma unroll
            for (int j = 0; j < 4; j++) {
                ps += acc[i][j][r] * avs[j];
                pd += acc[i][j][r] * avd[j];
            }
#pragma unroll
            for (int off = 1; off < 16; off <<= 1) {
                ps += __shfl_xor(ps, off);
                pd += __shfl_xor(pd, off);
            }
            if (lrow == 0) {
                int gr = rowBase + wm + i * 16 + lquad * 4 + r;
                al_s[gr * 4 + head] = ps;
                al_d[gr * 4 + head] = pd;
            }
        }
        // bf16 h store
        int grb = rowBase + wm + i * 16 + lquad * 4;
#pragma unroll
        for (int j = 0; j < 4; j++) {
            int gc = colBase + wn + j * 16 + lrow;
#pragma unroll
            for (int r = 0; r < 4; r++)
                Hbf[(size_t)(grb + r) * NCOL + gc] = f2bf(acc[i][j][r]);
        }
    }
}

// ---------------- bf16 MFMA GEMM, fp32 out (+bias, +lrelu) ----------------
// C[M,N] = A[M,K]_bf16 @ Bt[Npad,K]_bf16^T ; grid (Npad/128, M/128)
__global__ __launch_bounds__(256) void gemm_mfma(
    const ushort_t* __restrict__ A, const ushort_t* __restrict__ Bt,
    const float* __restrict__ bias, float* __restrict__ C,
    int M, int N, int K, int act, float slope) {
    __shared__ __align__(16) ushort_t As[128 * LDA];
    __shared__ __align__(16) ushort_t Bs[128 * LDA];
    int t = threadIdx.x;
    int wave = t >> 6, lane = t & 63;
    int wm = (wave >> 1) << 6;
    int wn = (wave & 1) << 6;
    int rowBase = blockIdx.y << 7;
    int colBase = blockIdx.x << 7;
    int lrow = lane & 15, lquad = lane >> 4;
    floatx4 acc[4][4];
#pragma unroll
    for (int i = 0; i < 4; i++)
#pragma unroll
        for (int j = 0; j < 4; j++) acc[i][j] = (floatx4){0.f, 0.f, 0.f, 0.f};

    int srow = t >> 2;
    int sko  = (t & 3) * 8;
    const ushort8 zero8 = {0, 0, 0, 0, 0, 0, 0, 0};

    for (int k0 = 0; k0 < K; k0 += 32) {
        bool kin = (k0 + sko + 8) <= K;
#pragma unroll
        for (int half = 0; half < 2; half++) {
            int row = srow + half * 64;
            ushort8 va = kin ? *(const ushort8*)(A + (size_t)(rowBase + row) * K + k0 + sko)
                             : zero8;
            *(ushort8*)(As + row * LDA + sko) = va;
            ushort8 vb = kin ? *(const ushort8*)(Bt + (size_t)(colBase + row) * K + k0 + sko)
                             : zero8;
            *(ushort8*)(Bs + row * LDA + sko) = vb;
        }
        __syncthreads();
        bf16x8 af[4], bfv[4];
#pragma unroll
        for (int i = 0; i < 4; i++)
            af[i] = *(const bf16x8*)(As + (wm + i * 16 + lrow) * LDA + lquad * 8);
#pragma unroll
        for (int j = 0; j < 4; j++)
            bfv[j] = *(const bf16x8*)(Bs + (wn + j * 16 + lrow) * LDA + lquad * 8);
#pragma unroll
        for (int i = 0; i < 4; i++)
#pragma unroll
            for (int j = 0; j < 4; j++)
                acc[i][j] = __builtin_amdgcn_mfma_f32_16x16x32_bf16(af[i], bfv[j],
                                                                    acc[i][j], 0, 0, 0);
        __syncthreads();
    }
#pragma unroll
    for (int i = 0; i < 4; i++) {
        int gr = rowBase + wm + i * 16 + lquad * 4;
#pragma unroll
        for (int j = 0; j < 4; j++) {
            int gc = colBase + wn + j * 16 + lrow;
            if (gc >= N) continue;
            float b = bias ? bias[gc] : 0.f;
#pragma unroll
            for (int r = 0; r < 4; r++) {
                float v = acc[i][j][r] + b;
                if (act) v = lrelu(v, slope);
                C[(size_t)(gr + r) * N + gc] = v;
            }
        }
    }
}

// ---------------- fp32 tiled GEMM (small MLP edges) ----------------
__global__ __launch_bounds__(256) void gemm_f32(
    const float* __restrict__ A, const float* __restrict__ B,
    const float* __restrict__ bias, float* __restrict__ C,
    int M, int N, int K, int act, float slope) {
    __shared__ float As[64][17];
    __shared__ float Bs[16][64];
    int t = threadIdx.x;
    int tr = t >> 4, tc = t & 15;
    int rowBase = blockIdx.y * 64;
    int colBase = blockIdx.x * 64;
    float acc[4][4] = {};
    for (int k0 = 0; k0 < K; k0 += 16) {
        {
            int m = t >> 2;
            int k = (t & 3) * 4;
            int gr = rowBase + m;
#pragma unroll
            for (int i = 0; i < 4; i++) {
                int gk = k0 + k + i;
                As[m][k + i] = (gr < M && gk < K) ? A[(size_t)gr * K + gk] : 0.f;
            }
        }
        {
            int kk = t >> 4;
            int n = (t & 15) * 4;
            int gk = k0 + kk;
#pragma unroll
            for (int i = 0; i < 4; i++) {
                int gn = colBase + n + i;
                Bs[kk][n + i] = (gk < K && gn < N) ? B[(size_t)gk * N + gn] : 0.f;
            }
        }
        __syncthreads();
#pragma unroll
        for (int kk = 0; kk < 16; kk++) {
            float a[4], b[4];
#pragma unroll
            for (int i = 0; i < 4; i++) a[i] = As[tr * 4 + i][kk];
#pragma unroll
            for (int j = 0; j < 4; j++) b[j] = Bs[kk][tc * 4 + j];
#pragma unroll
            for (int i = 0; i < 4; i++)
#pragma unroll
                for (int j = 0; j < 4; j++) acc[i][j] += a[i] * b[j];
        }
        __syncthreads();
    }
#pragma unroll
    for (int i = 0; i < 4; i++) {
        int r = rowBase + tr * 4 + i;
        if (r >= M) continue;
#pragma unroll
        for (int j = 0; j < 4; j++) {
            int c = colBase + tc * 4 + j;
            if (c >= N) continue;
            float v = acc[i][j] + (bias ? bias[c] : 0.f);
            if (act) v = lrelu(v, slope);
            C[(size_t)r * N + c] = v;
        }
    }
}

// ---------------- fused online-softmax aggregation: one wave per node ----------
// reads bf16 h rows (512 B each), writes bf16 aggregated h (+bias, +lrelu)
__global__ __launch_bounds__(256) void gat_agg(
    const ushort_t* __restrict__ h_bf, const float* __restrict__ al_s,
    const float* __restrict__ al_d, const int* __restrict__ row_ptr,
    const int* __restrict__ col, const float* __restrict__ bias,
    ushort_t* __restrict__ out_bf, int N, int act, float slope) {
    int gw = (blockIdx.x * 256 + threadIdx.x) >> 6;   // node id, wave-uniform
    if (gw >= N) return;
    int lane = threadIdx.x & 63;
    int head = lane >> 4;
    int idx = gw * 4 + head;
    float ad = al_d[idx];
    // self loop initializes the online state (p_self = 1 at m = e_self)
    float m = lrelu(al_s[idx] + ad, GAT_SLOPE);
    float s = 1.f;
    const ushort4v* h4 = (const ushort4v*)h_bf;
    ushort4v hv = h4[(size_t)gw * 64 + lane];
    float4 acc;
    acc.x = bf2f(hv.x); acc.y = bf2f(hv.y); acc.z = bf2f(hv.z); acc.w = bf2f(hv.w);
    int beg = row_ptr[gw], end = row_ptr[gw + 1];
    for (int i = beg; i < end; i++) {
        int src = col[i];
        float e = lrelu(al_s[src * 4 + head] + ad, GAT_SLOPE);
        float mn = fmaxf(m, e);
        float scale = __expf(m - mn);
        float p = __expf(e - mn);
        ushort4v hs = h4[(size_t)src * 64 + lane];
        acc.x = acc.x * scale + p * bf2f(hs.x);
        acc.y = acc.y * scale + p * bf2f(hs.y);
        acc.z = acc.z * scale + p * bf2f(hs.z);
        acc.w = acc.w * scale + p * bf2f(hs.w);
        s = s * scale + p;
        m = mn;
    }
    float rs = 1.f / s;
    float4 bv = ((const float4*)bias)[lane];
    acc.x = acc.x * rs + bv.x; acc.y = acc.y * rs + bv.y;
    acc.z = acc.z * rs + bv.z; acc.w = acc.w * rs + bv.w;
    if (act) {
        acc.x = lrelu(acc.x, slope); acc.y = lrelu(acc.y, slope);
        acc.z = lrelu(acc.z, slope); acc.w = lrelu(acc.w, slope);
    }
    ushort4v o;
    o.x = f2bf(acc.x); o.y = f2bf(acc.y); o.z = f2bf(acc.z); o.w = f2bf(acc.w);
    ((ushort4v*)out_bf)[(size_t)gw * 64 + lane] = o;
}

// ---------------------------------------------------------------------------
extern "C" void kernel_launch(void* const* d_in, const int* in_sizes, int n_in,
                              void* d_out, int out_size, void* d_ws, size_t ws_size,
                              hipStream_t stream) {
    const float* x        = (const float*)d_in[0];
    const int*   rawEdge  = (const int*)d_in[1];
    const float* rootCtx  = (const float*)d_in[2];
    const float* W[3]     = {(const float*)d_in[3], (const float*)d_in[7], (const float*)d_in[11]};
    const float* aS[3]    = {(const float*)d_in[4], (const float*)d_in[8], (const float*)d_in[12]};
    const float* aD[3]    = {(const float*)d_in[5], (const float*)d_in[9], (const float*)d_in[13]};
    const float* bb[3]    = {(const float*)d_in[6], (const float*)d_in[10], (const float*)d_in[14]};
    const float* fc_w     = (const float*)d_in[15];
    const float* fc_b     = (const float*)d_in[16];
    const float* r_w1     = (const float*)d_in[17];
    const float* r_b1     = (const float*)d_in[18];
    const float* r_w2     = (const float*)d_in[19];
    const float* r_b2     = (const float*)d_in[20];
    const float* r_w3     = (const float*)d_in[21];
    const float* r_b3     = (const float*)d_in[22];

    const int N  = in_sizes[0] / 80;      // 102400
    const int E  = in_sizes[1] / 2;       // 409600
    const int R  = in_sizes[2] / 60;      // 4096
    const int N4 = N * 4;
    const int HC = 256;

    float* outRot  = (float*)d_out;                  // [N, 80]
    float* outRoot = (float*)d_out + (size_t)N * 80; // [R, 60]

    // ---- carve workspace ----
    size_t off = 0;
    auto carve = [&](size_t bytes) -> void* {
        off = (off + 255) & ~(size_t)255;
        void* p = (char*)d_ws + off;
        off += bytes;
        return p;
    };
    int*      flag      = (int*)carve(4);
    int*      idx32     = (int*)carve((size_t)2 * E * 4);
    int*      counts    = (int*)carve((size_t)N * 4);
    int*      cursor    = (int*)carve((size_t)N * 4);
    int*      row_ptr   = (int*)carve((size_t)(N + 1) * 4);
    int*      incArr    = (int*)carve((size_t)N * 4);
    int*      blockSums = (int*)carve(512 * 4);
    int*      colArr    = (int*)carve((size_t)E * 4);
    float*    al_s      = (float*)carve((size_t)N4 * 4);
    float*    al_d      = (float*)carve((size_t)N4 * 4);
    ushort_t* h_bf      = (ushort_t*)carve((size_t)N * HC * 2);   // GEMM out (pre-agg)
    ushort_t* agg_bf    = (ushort_t*)carve((size_t)N * HC * 2);   // agg out / next GEMM in
    ushort_t* x_bf      = (ushort_t*)carve((size_t)N * 80 * 2);
    float*    t1        = (float*)carve((size_t)R * 512 * 4);
    float*    t2        = (float*)carve((size_t)R * 512 * 4);
    ushort_t* t1_bf     = (ushort_t*)carve((size_t)R * 512 * 2);
    ushort_t* Wt0       = (ushort_t*)carve((size_t)256 * 80 * 2);
    ushort_t* Wt1       = (ushort_t*)carve((size_t)256 * 256 * 2);
    ushort_t* Wt2       = (ushort_t*)carve((size_t)256 * 256 * 2);
    ushort_t* fcWt      = (ushort_t*)carve((size_t)128 * 256 * 2);
    ushort_t* rWt2      = (ushort_t*)carve((size_t)512 * 512 * 2);

    const int nb = (N + 255) / 256;
    dim3 blk(256);

    // ---- edge format + CSR build ----
    detect_fmt<<<1, 256, 0, stream>>>(rawEdge, 2 * E, flag);
    convert_idx<<<(2 * E + 255) / 256, 256, 0, stream>>>(rawEdge, 2 * E, flag, idx32);
    const int* srcArr = idx32;
    const int* dstArr = idx32 + E;
    zero_ints<<<(N + 255) / 256, 256, 0, stream>>>(counts, N);
    zero_ints<<<(N + 255) / 256, 256, 0, stream>>>(cursor, N);
    edge_count<<<(E + 255) / 256, 256, 0, stream>>>(dstArr, E, counts);
    scan_block<<<nb, 256, 0, stream>>>(counts, incArr, blockSums, N);
    scan_sums<<<1, 512, 0, stream>>>(blockSums, nb, row_ptr);
    scan_add<<<nb, 256, 0, stream>>>(incArr, blockSums, row_ptr, N);
    edge_fill<<<(E + 255) / 256, 256, 0, stream>>>(srcArr, dstArr, E, row_ptr, cursor, colArr);

    // ---- weight + input conversions ----
    convert_w<<<(256 * 80 + 255) / 256, blk, 0, stream>>>(W[0], Wt0, 80, 256, 256);
    convert_w<<<(256 * 256 + 255) / 256, blk, 0, stream>>>(W[1], Wt1, 256, 256, 256);
    convert_w<<<(256 * 256 + 255) / 256, blk, 0, stream>>>(W[2], Wt2, 256, 256, 256);
    convert_w<<<(128 * 256 + 255) / 256, blk, 0, stream>>>(fc_w, fcWt, 256, 80, 128);
    convert_w<<<(512 * 512 + 255) / 256, blk, 0, stream>>>(r_w2, rWt2, 512, 512, 512);
    convert_bf4<<<(N * 80 / 4 + 255) / 256, blk, 0, stream>>>(x, x_bf, N * 80 / 4);

    // ---- GAT layers ----
    const ushort_t* curA = x_bf;
    int curK = 80;
    for (int l = 0; l < 3; l++) {
        dim3 g1(2, N / 128);
        gemm_mfma_gat<<<g1, blk, 0, stream>>>(curA, l == 0 ? Wt0 : (l == 1 ? Wt1 : Wt2),
                                              aS[l], aD[l], h_bf, al_s, al_d, N, curK);
        int act = (l < 2) ? 1 : 0;
        gat_agg<<<(N * 64 + 255) / 256, blk, 0, stream>>>(h_bf, al_s, al_d, row_ptr,
                                                          colArr, bb[l], agg_bf, N,
                                                          act, ACT_SLOPE);
        curA = agg_bf;
        curK = HC;
    }

    // ---- rot = h @ fc_w + fc_b  (N=80 real, tile padded to 128) ----
    {
        dim3 g(1, N / 128);
        gemm_mfma<<<g, blk, 0, stream>>>(agg_bf, fcWt, fc_b, outRot, N, 80, HC, 0, 0.f);
    }
    // ---- MLP branch ----
    {
        dim3 g1((512 + 63) / 64, (R + 63) / 64);
        gemm_f32<<<g1, blk, 0, stream>>>(rootCtx, r_w1, r_b1, t1, R, 512, 60, 1, ACT_SLOPE);
        convert_bf4<<<(R * 512 / 4 + 255) / 256, blk, 0, stream>>>(t1, t1_bf, R * 512 / 4);
        dim3 g2(512 / 128, R / 128);
        gemm_mfma<<<g2, blk, 0, stream>>>(t1_bf, rWt2, r_b2, t2, R, 512, 512, 1, ACT_SLOPE);
        dim3 g3((60 + 63) / 64, (R + 63) / 64);
        gemm_f32<<<g3, blk, 0, stream>>>(t2, r_w3, r_b3, outRoot, R, 60, 512, 0, 0.f);
    }
}

// Round 4
// 541.986 us; speedup vs baseline: 3.1462x; 1.2049x over previous
//
#include <hip/hip_runtime.h>
#include <hip/hip_bf16.h>

// ---------------------------------------------------------------------------
// GAT x3 + fc + MLP. GEMMs bf16 MFMA (16x16x32). R4:
//  - gat_agg: no-max softmax (logits bounded), lrelu=max(x,s*x), software
//    prefetch of next edge, scalar row_ptr/col via readfirstlane.
//  - MLP branch all-MFMA (K 60->64 pad, bf16 chaining), gemm_f32 removed.
//  - CSR: convert+count fused; weight transposes merged into one kernel.
// ---------------------------------------------------------------------------

#define GAT_SLOPE 0.2f
#define ACT_SLOPE 0.01f

typedef unsigned short ushort_t;
typedef __attribute__((ext_vector_type(8))) short bf16x8;
typedef __attribute__((ext_vector_type(8))) unsigned short ushort8;
typedef __attribute__((ext_vector_type(4))) unsigned short ushort4v;
typedef __attribute__((ext_vector_type(4))) float floatx4;

__device__ __forceinline__ float lrelu(float x, float s) {
    return fmaxf(x, s * x);   // valid for 0<s<1
}

__device__ __forceinline__ ushort_t f2bf(float f) {
    union { float f; unsigned u; } x; x.f = f;
    unsigned r = x.u + 0x7FFF + ((x.u >> 16) & 1);   // round-nearest-even
    return (ushort_t)(r >> 16);
}

__device__ __forceinline__ float bf2f(ushort_t u) {
    union { unsigned u; float f; } x; x.u = ((unsigned)u) << 16;
    return x.f;
}

// ---------------- edge-index format probe ----------------
__global__ void detect_fmt(const int* __restrict__ raw, int nwords, int* flag) {
    __shared__ int nz;
    if (threadIdx.x == 0) nz = 0;
    __syncthreads();
    int lim = nwords < 4096 ? nwords : 4096;
    for (int i = threadIdx.x * 2 + 1; i < lim; i += 512)
        if (raw[i] != 0) atomicAdd(&nz, 1);
    __syncthreads();
    if (threadIdx.x == 0) *flag = (nz == 0) ? 1 : 0;   // 1 => int64 storage
}

__global__ void zero2(int* __restrict__ a, int* __restrict__ b, int n) {
    int i = blockIdx.x * blockDim.x + threadIdx.x;
    if (i < n) { a[i] = 0; b[i] = 0; }
}

// convert both halves + count dst in one pass
__global__ void convert_count(const int* __restrict__ raw, int E,
                              const int* __restrict__ flag,
                              int* __restrict__ idx32, int* __restrict__ counts) {
    int i = blockIdx.x * blockDim.x + threadIdx.x;
    if (i >= E) return;
    int f = *flag;
    int s = f ? raw[2 * i] : raw[i];
    int d = f ? raw[2 * (E + i)] : raw[E + i];
    idx32[i] = s;
    idx32[E + i] = d;
    atomicAdd(&counts[d], 1);
}

__global__ void scan_block(const int* __restrict__ counts, int* __restrict__ inc,
                           int* __restrict__ blockSums, int N) {
    __shared__ int sh[256];
    int i = blockIdx.x * 256 + threadIdx.x;
    int v = (i < N) ? counts[i] : 0;
    sh[threadIdx.x] = v;
    __syncthreads();
    for (int off = 1; off < 256; off <<= 1) {
        int t = (threadIdx.x >= off) ? sh[threadIdx.x - off] : 0;
        __syncthreads();
        sh[threadIdx.x] += t;
        __syncthreads();
    }
    if (i < N) inc[i] = sh[threadIdx.x];
    if (threadIdx.x == 255) blockSums[blockIdx.x] = sh[255];
}

__global__ void scan_sums(int* __restrict__ blockSums, int nb, int* __restrict__ row_ptr) {
    __shared__ int sh[512];
    int v = ((int)threadIdx.x < nb) ? blockSums[threadIdx.x] : 0;
    sh[threadIdx.x] = v;
    __syncthreads();
    for (int off = 1; off < 512; off <<= 1) {
        int t = (threadIdx.x >= off) ? sh[threadIdx.x - off] : 0;
        __syncthreads();
        sh[threadIdx.x] += t;
        __syncthreads();
    }
    if ((int)threadIdx.x < nb) blockSums[threadIdx.x] = sh[threadIdx.x];
    if (threadIdx.x == 0) row_ptr[0] = 0;
}

__global__ void scan_add(const int* __restrict__ inc, const int* __restrict__ blockSums,
                         int* __restrict__ row_ptr, int N) {
    int i = blockIdx.x * 256 + threadIdx.x;
    if (i < N) row_ptr[i + 1] = inc[i] + (blockIdx.x > 0 ? blockSums[blockIdx.x - 1] : 0);
}

__global__ void edge_fill(const int* __restrict__ src, const int* __restrict__ dst, int E,
                          const int* __restrict__ row_ptr, int* __restrict__ cursor,
                          int* __restrict__ col) {
    int i = blockIdx.x * blockDim.x + threadIdx.x;
    if (i < E) {
        int d = dst[i];
        int pos = row_ptr[d] + atomicAdd(&cursor[d], 1);
        col[pos] = src[i];
    }
}

// ---------------- conversions ----------------
__global__ void convert_bf4(const float* __restrict__ in, ushort_t* __restrict__ out, int n4) {
    int i = blockIdx.x * blockDim.x + threadIdx.x;
    if (i >= n4) return;
    const float4 v = ((const float4*)in)[i];
    ushort4v o;
    o.x = f2bf(v.x); o.y = f2bf(v.y); o.z = f2bf(v.z); o.w = f2bf(v.w);
    ((ushort4v*)out)[i] = o;
}

// pad-convert rows: in [M][Kr] fp32 -> out [M][Kp] bf16, cols >= Kr zeroed
__global__ void convert_padrow(const float* __restrict__ in, ushort_t* __restrict__ out,
                               int M, int Kr, int Kp) {
    int i = blockIdx.x * blockDim.x + threadIdx.x;
    if (i >= M * Kp) return;
    int r = i / Kp, c = i - r * Kp;
    out[i] = f2bf((c < Kr) ? in[(size_t)r * Kr + c] : 0.f);
}

// merged weight transposes: in [Kr,N] fp32 -> out [Npad,Kp] bf16 (transposed,
// zero pad rows >= N and cols >= Kr)
struct WConv { const float* in; ushort_t* out; int Kp, Kr, N, Npad, blkOff; };
struct WConvArr { WConv e[7]; int n; };

__global__ void convert_w_multi(WConvArr a) {
    int b = blockIdx.x;
    int ei = 0;
    for (int k = 1; k < a.n; k++)
        if (b >= a.e[k].blkOff) ei = k;
    WConv w = a.e[ei];
    int i = (b - w.blkOff) * 256 + threadIdx.x;
    if (i >= w.Npad * w.Kp) return;
    int n = i / w.Kp, k = i - n * w.Kp;
    float v = (n < w.N && k < w.Kr) ? w.in[(size_t)k * w.N + n] : 0.f;
    w.out[i] = f2bf(v);
}

#define LDA 40   // padded LDS row (elements): row stride 80B -> 2-way bank alias only

// ---------------- fused GAT GEMM: H_bf16 = A @ W ; al_s/al_d from fp32 acc ----
__global__ __launch_bounds__(256) void gemm_mfma_gat(
    const ushort_t* __restrict__ A, const ushort_t* __restrict__ Bt,
    const float* __restrict__ a_src, const float* __restrict__ a_dst,
    ushort_t* __restrict__ Hbf, float* __restrict__ al_s, float* __restrict__ al_d,
    int M, int K) {
    const int NCOL = 256;
    __shared__ __align__(16) ushort_t As[128 * LDA];
    __shared__ __align__(16) ushort_t Bs[128 * LDA];
    int t = threadIdx.x;
    int wave = t >> 6, lane = t & 63;
    int wm = (wave >> 1) << 6;
    int wn = (wave & 1) << 6;
    int rowBase = blockIdx.y << 7;
    int colBase = blockIdx.x << 7;
    int lrow = lane & 15, lquad = lane >> 4;
    floatx4 acc[4][4];
#pragma unroll
    for (int i = 0; i < 4; i++)
#pragma unroll
        for (int j = 0; j < 4; j++) acc[i][j] = (floatx4){0.f, 0.f, 0.f, 0.f};

    int srow = t >> 2;
    int sko  = (t & 3) * 8;
    const ushort8 zero8 = {0, 0, 0, 0, 0, 0, 0, 0};

    for (int k0 = 0; k0 < K; k0 += 32) {
        bool kin = (k0 + sko + 8) <= K;
#pragma unroll
        for (int half = 0; half < 2; half++) {
            int row = srow + half * 64;
            ushort8 va = kin ? *(const ushort8*)(A + (size_t)(rowBase + row) * K + k0 + sko)
                             : zero8;
            *(ushort8*)(As + row * LDA + sko) = va;
            ushort8 vb = kin ? *(const ushort8*)(Bt + (size_t)(colBase + row) * K + k0 + sko)
                             : zero8;
            *(ushort8*)(Bs + row * LDA + sko) = vb;
        }
        __syncthreads();
        bf16x8 af[4], bfv[4];
#pragma unroll
        for (int i = 0; i < 4; i++)
            af[i] = *(const bf16x8*)(As + (wm + i * 16 + lrow) * LDA + lquad * 8);
#pragma unroll
        for (int j = 0; j < 4; j++)
            bfv[j] = *(const bf16x8*)(Bs + (wn + j * 16 + lrow) * LDA + lquad * 8);
#pragma unroll
        for (int i = 0; i < 4; i++)
#pragma unroll
            for (int j = 0; j < 4; j++)
                acc[i][j] = __builtin_amdgcn_mfma_f32_16x16x32_bf16(af[i], bfv[j],
                                                                    acc[i][j], 0, 0, 0);
        __syncthreads();
    }
    int head = (colBase + wn) >> 6;
    float avs[4], avd[4];
#pragma unroll
    for (int j = 0; j < 4; j++) {
        avs[j] = a_src[head * 64 + j * 16 + lrow];
        avd[j] = a_dst[head * 64 + j * 16 + lrow];
    }
#pragma unroll
    for (int i = 0; i < 4; i++) {
#pragma unroll
        for (int r = 0; r < 4; r++) {
            float ps = 0.f, pd = 0.f;
#pragma unroll
            for (int j = 0; j < 4; j++) {
                ps += acc[i][j][r] * avs[j];
                pd += acc[i][j][r] * avd[j];
            }
#pragma unroll
            for (int off = 1; off < 16; off <<= 1) {
                ps += __shfl_xor(ps, off);
                pd += __shfl_xor(pd, off);
            }
            if (lrow == 0) {
                int gr = rowBase + wm + i * 16 + lquad * 4 + r;
                al_s[gr * 4 + head] = ps;
                al_d[gr * 4 + head] = pd;
            }
        }
        int grb = rowBase + wm + i * 16 + lquad * 4;
#pragma unroll
        for (int j = 0; j < 4; j++) {
            int gc = colBase + wn + j * 16 + lrow;
#pragma unroll
            for (int r = 0; r < 4; r++)
                Hbf[(size_t)(grb + r) * NCOL + gc] = f2bf(acc[i][j][r]);
        }
    }
}

// ---------------- bf16 MFMA GEMM (+bias, +lrelu), fp32 or bf16 out ----------
__global__ __launch_bounds__(256) void gemm_mfma(
    const ushort_t* __restrict__ A, const ushort_t* __restrict__ Bt,
    const float* __restrict__ bias, void* __restrict__ Cout,
    int M, int N, int K, int act, float slope, int outBf) {
    __shared__ __align__(16) ushort_t As[128 * LDA];
    __shared__ __align__(16) ushort_t Bs[128 * LDA];
    int t = threadIdx.x;
    int wave = t >> 6, lane = t & 63;
    int wm = (wave >> 1) << 6;
    int wn = (wave & 1) << 6;
    int rowBase = blockIdx.y << 7;
    int colBase = blockIdx.x << 7;
    int lrow = lane & 15, lquad = lane >> 4;
    floatx4 acc[4][4];
#pragma unroll
    for (int i = 0; i < 4; i++)
#pragma unroll
        for (int j = 0; j < 4; j++) acc[i][j] = (floatx4){0.f, 0.f, 0.f, 0.f};

    int srow = t >> 2;
    int sko  = (t & 3) * 8;
    const ushort8 zero8 = {0, 0, 0, 0, 0, 0, 0, 0};

    for (int k0 = 0; k0 < K; k0 += 32) {
        bool kin = (k0 + sko + 8) <= K;
#pragma unroll
        for (int half = 0; half < 2; half++) {
            int row = srow + half * 64;
            ushort8 va = kin ? *(const ushort8*)(A + (size_t)(rowBase + row) * K + k0 + sko)
                             : zero8;
            *(ushort8*)(As + row * LDA + sko) = va;
            ushort8 vb = kin ? *(const ushort8*)(Bt + (size_t)(colBase + row) * K + k0 + sko)
                             : zero8;
            *(ushort8*)(Bs + row * LDA + sko) = vb;
        }
        __syncthreads();
        bf16x8 af[4], bfv[4];
#pragma unroll
        for (int i = 0; i < 4; i++)
            af[i] = *(const bf16x8*)(As + (wm + i * 16 + lrow) * LDA + lquad * 8);
#pragma unroll
        for (int j = 0; j < 4; j++)
            bfv[j] = *(const bf16x8*)(Bs + (wn + j * 16 + lrow) * LDA + lquad * 8);
#pragma unroll
        for (int i = 0; i < 4; i++)
#pragma unroll
            for (int j = 0; j < 4; j++)
                acc[i][j] = __builtin_amdgcn_mfma_f32_16x16x32_bf16(af[i], bfv[j],
                                                                    acc[i][j], 0, 0, 0);
        __syncthreads();
    }
#pragma unroll
    for (int i = 0; i < 4; i++) {
        int gr = rowBase + wm + i * 16 + lquad * 4;
#pragma unroll
        for (int j = 0; j < 4; j++) {
            int gc = colBase + wn + j * 16 + lrow;
            if (gc >= N) continue;
            float b = bias ? bias[gc] : 0.f;
#pragma unroll
            for (int r = 0; r < 4; r++) {
                float v = acc[i][j][r] + b;
                if (act) v = lrelu(v, slope);
                if (outBf)
                    ((ushort_t*)Cout)[(size_t)(gr + r) * N + gc] = f2bf(v);
                else
                    ((float*)Cout)[(size_t)(gr + r) * N + gc] = v;
            }
        }
    }
}

// ---------------- aggregation: one wave per node, no-max softmax ------------
__global__ __launch_bounds__(256) void gat_agg(
    const ushort_t* __restrict__ h_bf, const float* __restrict__ al_s,
    const float* __restrict__ al_d, const int* __restrict__ row_ptr,
    const int* __restrict__ col, const float* __restrict__ bias,
    ushort_t* __restrict__ out_bf, int N, int act, float slope) {
    int gw = __builtin_amdgcn_readfirstlane((blockIdx.x * 256 + threadIdx.x) >> 6);
    if (gw >= N) return;
    int lane = threadIdx.x & 63;
    int head = lane >> 4;
    int idx = gw * 4 + head;
    float ad = al_d[idx];
    const ushort4v* h4 = (const ushort4v*)h_bf;
    // self loop
    float p = __expf(lrelu(al_s[idx] + ad, GAT_SLOPE));
    ushort4v hv = h4[(size_t)gw * 64 + lane];
    float s = p;
    float4 acc;
    acc.x = p * bf2f(hv.x); acc.y = p * bf2f(hv.y);
    acc.z = p * bf2f(hv.z); acc.w = p * bf2f(hv.w);
    int beg = row_ptr[gw], end = row_ptr[gw + 1];
    int i = beg;
    ushort4v hN = {0, 0, 0, 0};
    float alN = 0.f;
    if (i < end) {
        int sn = col[i];
        hN = h4[(size_t)sn * 64 + lane];
        alN = al_s[sn * 4 + head];
    }
    while (i < end) {
        ushort4v hC = hN;
        float alC = alN;
        ++i;
        if (i < end) {                         // prefetch next edge
            int sn = col[i];
            hN = h4[(size_t)sn * 64 + lane];
            alN = al_s[sn * 4 + head];
        }
        float pe = __expf(lrelu(alC + ad, GAT_SLOPE));
        acc.x += pe * bf2f(hC.x); acc.y += pe * bf2f(hC.y);
        acc.z += pe * bf2f(hC.z); acc.w += pe * bf2f(hC.w);
        s += pe;
    }
    float rs = 1.f / s;
    float4 bv = ((const float4*)bias)[lane];
    acc.x = acc.x * rs + bv.x; acc.y = acc.y * rs + bv.y;
    acc.z = acc.z * rs + bv.z; acc.w = acc.w * rs + bv.w;
    if (act) {
        acc.x = lrelu(acc.x, slope); acc.y = lrelu(acc.y, slope);
        acc.z = lrelu(acc.z, slope); acc.w = lrelu(acc.w, slope);
    }
    ushort4v o;
    o.x = f2bf(acc.x); o.y = f2bf(acc.y); o.z = f2bf(acc.z); o.w = f2bf(acc.w);
    ((ushort4v*)out_bf)[(size_t)gw * 64 + lane] = o;
}

// ---------------------------------------------------------------------------
extern "C" void kernel_launch(void* const* d_in, const int* in_sizes, int n_in,
                              void* d_out, int out_size, void* d_ws, size_t ws_size,
                              hipStream_t stream) {
    const float* x        = (const float*)d_in[0];
    const int*   rawEdge  = (const int*)d_in[1];
    const float* rootCtx  = (const float*)d_in[2];
    const float* W[3]     = {(const float*)d_in[3], (const float*)d_in[7], (const float*)d_in[11]};
    const float* aS[3]    = {(const float*)d_in[4], (const float*)d_in[8], (const float*)d_in[12]};
    const float* aD[3]    = {(const float*)d_in[5], (const float*)d_in[9], (const float*)d_in[13]};
    const float* bb[3]    = {(const float*)d_in[6], (const float*)d_in[10], (const float*)d_in[14]};
    const float* fc_w     = (const float*)d_in[15];
    const float* fc_b     = (const float*)d_in[16];
    const float* r_w1     = (const float*)d_in[17];
    const float* r_b1     = (const float*)d_in[18];
    const float* r_w2     = (const float*)d_in[19];
    const float* r_b2     = (const float*)d_in[20];
    const float* r_w3     = (const float*)d_in[21];
    const float* r_b3     = (const float*)d_in[22];

    const int N  = in_sizes[0] / 80;      // 102400
    const int E  = in_sizes[1] / 2;       // 409600
    const int R  = in_sizes[2] / 60;      // 4096
    const int N4 = N * 4;
    const int HC = 256;

    float* outRot  = (float*)d_out;                  // [N, 80]
    float* outRoot = (float*)d_out + (size_t)N * 80; // [R, 60]

    // ---- carve workspace ----
    size_t off = 0;
    auto carve = [&](size_t bytes) -> void* {
        off = (off + 255) & ~(size_t)255;
        void* p = (char*)d_ws + off;
        off += bytes;
        return p;
    };
    int*      flag      = (int*)carve(4);
    int*      idx32     = (int*)carve((size_t)2 * E * 4);
    int*      counts    = (int*)carve((size_t)N * 4);
    int*      cursor    = (int*)carve((size_t)N * 4);
    int*      row_ptr   = (int*)carve((size_t)(N + 1) * 4);
    int*      incArr    = (int*)carve((size_t)N * 4);
    int*      blockSums = (int*)carve(512 * 4);
    int*      colArr    = (int*)carve((size_t)E * 4);
    float*    al_s      = (float*)carve((size_t)N4 * 4);
    float*    al_d      = (float*)carve((size_t)N4 * 4);
    ushort_t* h_bf      = (ushort_t*)carve((size_t)N * HC * 2);
    ushort_t* agg_bf    = (ushort_t*)carve((size_t)N * HC * 2);
    ushort_t* x_bf      = (ushort_t*)carve((size_t)N * 80 * 2);
    ushort_t* rc_bf     = (ushort_t*)carve((size_t)R * 64 * 2);
    ushort_t* t1_bf     = (ushort_t*)carve((size_t)R * 512 * 2);
    ushort_t* t2_bf     = (ushort_t*)carve((size_t)R * 512 * 2);
    ushort_t* Wt0       = (ushort_t*)carve((size_t)256 * 80 * 2);
    ushort_t* Wt1       = (ushort_t*)carve((size_t)256 * 256 * 2);
    ushort_t* Wt2       = (ushort_t*)carve((size_t)256 * 256 * 2);
    ushort_t* fcWt      = (ushort_t*)carve((size_t)128 * 256 * 2);
    ushort_t* rW1t      = (ushort_t*)carve((size_t)512 * 64 * 2);
    ushort_t* rWt2      = (ushort_t*)carve((size_t)512 * 512 * 2);
    ushort_t* rWt3      = (ushort_t*)carve((size_t)128 * 512 * 2);

    const int nb = (N + 255) / 256;
    dim3 blk(256);

    // ---- edge format + CSR build ----
    detect_fmt<<<1, 256, 0, stream>>>(rawEdge, 2 * E, flag);
    zero2<<<(N + 255) / 256, blk, 0, stream>>>(counts, cursor, N);
    convert_count<<<(E + 255) / 256, blk, 0, stream>>>(rawEdge, E, flag, idx32, counts);
    const int* srcArr = idx32;
    const int* dstArr = idx32 + E;
    scan_block<<<nb, 256, 0, stream>>>(counts, incArr, blockSums, N);
    scan_sums<<<1, 512, 0, stream>>>(blockSums, nb, row_ptr);
    scan_add<<<nb, 256, 0, stream>>>(incArr, blockSums, row_ptr, N);
    edge_fill<<<(E + 255) / 256, blk, 0, stream>>>(srcArr, dstArr, E, row_ptr, cursor, colArr);

    // ---- weight conversions (merged) ----
    {
        WConvArr wa;
        auto mk = [&](int i, const float* in, ushort_t* out, int Kp, int Kr, int Nn, int Npad,
                      int blkOff) {
            wa.e[i] = WConv{in, out, Kp, Kr, Nn, Npad, blkOff};
        };
        int boff = 0;
        auto nblk = [](int Npad, int Kp) { return (Npad * Kp + 255) / 256; };
        mk(0, W[0], Wt0, 80, 80, 256, 256, boff);  boff += nblk(256, 80);
        mk(1, W[1], Wt1, 256, 256, 256, 256, boff); boff += nblk(256, 256);
        mk(2, W[2], Wt2, 256, 256, 256, 256, boff); boff += nblk(256, 256);
        mk(3, fc_w, fcWt, 256, 256, 80, 128, boff); boff += nblk(128, 256);
        mk(4, r_w1, rW1t, 64, 60, 512, 512, boff);  boff += nblk(512, 64);
        mk(5, r_w2, rWt2, 512, 512, 512, 512, boff); boff += nblk(512, 512);
        mk(6, r_w3, rWt3, 512, 512, 60, 128, boff);  boff += nblk(128, 512);
        wa.n = 7;
        convert_w_multi<<<boff, blk, 0, stream>>>(wa);
    }
    convert_bf4<<<(N * 80 / 4 + 255) / 256, blk, 0, stream>>>(x, x_bf, N * 80 / 4);
    convert_padrow<<<(R * 64 + 255) / 256, blk, 0, stream>>>(rootCtx, rc_bf, R, 60, 64);

    // ---- GAT layers ----
    const ushort_t* curA = x_bf;
    int curK = 80;
    for (int l = 0; l < 3; l++) {
        dim3 g1(2, N / 128);
        gemm_mfma_gat<<<g1, blk, 0, stream>>>(curA, l == 0 ? Wt0 : (l == 1 ? Wt1 : Wt2),
                                              aS[l], aD[l], h_bf, al_s, al_d, N, curK);
        int act = (l < 2) ? 1 : 0;
        gat_agg<<<(N * 64 + 255) / 256, blk, 0, stream>>>(h_bf, al_s, al_d, row_ptr,
                                                          colArr, bb[l], agg_bf, N,
                                                          act, ACT_SLOPE);
        curA = agg_bf;
        curK = HC;
    }

    // ---- rot = h @ fc_w + fc_b ----
    {
        dim3 g(1, N / 128);
        gemm_mfma<<<g, blk, 0, stream>>>(agg_bf, fcWt, fc_b, outRot, N, 80, HC, 0, 0.f, 0);
    }
    // ---- MLP branch (all MFMA, bf16 chaining) ----
    {
        dim3 g1(512 / 128, R / 128);
        gemm_mfma<<<g1, blk, 0, stream>>>(rc_bf, rW1t, r_b1, t1_bf, R, 512, 64,
                                          1, ACT_SLOPE, 1);
        dim3 g2(512 / 128, R / 128);
        gemm_mfma<<<g2, blk, 0, stream>>>(t1_bf, rWt2, r_b2, t2_bf, R, 512, 512,
                                          1, ACT_SLOPE, 1);
        dim3 g3(1, R / 128);
        gemm_mfma<<<g3, blk, 0, stream>>>(t2_bf, rWt3, r_b3, outRoot, R, 60, 512,
                                          0, 0.f, 0);
    }
}